// Round 8
// baseline (23.810 us; speedup 1.0000x reference)
//
#include <hip/hip_runtime.h>
#include <math.h>

#define NQ    12
#define DIM   4096
#define BATCH 512

// One butterfly level over the 64 register-resident amplitudes (32 pairs).
// Gate q (acting on state bit 11-q): g00 = (c, 0) is REAL -> 14 FMA/pair.
#define LEVEL(q, J) do {                                                    \
    const float c    = g[q][0];                                             \
    const float g01r = g[q][2], g01i = g[q][3];                             \
    const float g10r = g[q][4], g10i = g[q][5];                             \
    const float g11r = g[q][6], g11i = g[q][7];                             \
    _Pragma("unroll")                                                       \
    for (int p = 0; p < 32; ++p) {                                          \
        const int r0 = ((p >> (J)) << ((J) + 1)) | (p & ((1 << (J)) - 1));  \
        const int r1 = r0 | (1 << (J));                                     \
        const float ar = xr[r0], ai = xi[r0];                               \
        const float br = xr[r1], bi = xi[r1];                               \
        xr[r0] = c * ar + (g01r * br - g01i * bi);                          \
        xi[r0] = c * ai + (g01r * bi + g01i * br);                          \
        xr[r1] = (g10r * ar - g10i * ai) + (g11r * br - g11i * bi);         \
        xi[r1] = (g10r * ai + g10i * ar) + (g11r * bi + g11i * br);         \
    }                                                                       \
} while (0)

// One wave (64 lanes) per batch element. 64 amps/lane in registers.
// No inter-wave sync anywhere: 6 register levels, one XOR-swizzled LDS
// transpose, 6 register levels, store.
__global__ __launch_bounds__(64) void u3_wave_kernel(
    const float* __restrict__ thetas,   // [12,3]
    const float* __restrict__ sre,      // [512,4096]
    const float* __restrict__ sim_,     // [512,4096]
    float*       __restrict__ out)      // [512,4096,2]
{
    __shared__ float Lr[DIM];           // 16 KB
    __shared__ float Li[DIM];           // 16 KB
    __shared__ __align__(16) float g[NQ][8];

    const int e = blockIdx.x;           // element
    const int t = threadIdx.x;          // lane 0..63

    // ---- issue global loads first: lane owns amps [t*64, t*64+64) ----
    // (idx bits 11:6 = lane, bits 5:0 = register)
    const float4* pre = (const float4*)(sre  + (size_t)e * DIM + t * 64);
    const float4* pim = (const float4*)(sim_ + (size_t)e * DIM + t * 64);
    float xr[64], xi[64];
#pragma unroll
    for (int k = 0; k < 16; ++k) {
        *(float4*)&xr[4 * k] = pre[k];
        *(float4*)&xi[4 * k] = pim[k];
    }

    // ---- gates (lanes 0..11); gate q acts on state bit (11-q) ----
    if (t < NQ) {
        float th = thetas[t * 3 + 0];
        float ph = thetas[t * 3 + 1];
        float la = thetas[t * 3 + 2];
        float c, s, cl, sl, cp, sp;
        __sincosf(th * 0.5f, &s, &c);
        __sincosf(la, &sl, &cl);
        __sincosf(ph, &sp, &cp);
        g[t][0] = c;        g[t][1] = 0.0f;
        g[t][2] = -cl * s;  g[t][3] = -sl * s;
        g[t][4] = cp * s;   g[t][5] = sp * s;
        g[t][6] = (cp * cl - sp * sl) * c;
        g[t][7] = (sp * cl + cp * sl) * c;
    }
    __syncthreads();    // single wave: ~free; orders gate LDS writes

    // ---- levels on state bits 0..5 (register-local) -> gates 11..6 ----
    LEVEL(11, 0); LEVEL(10, 1); LEVEL(9, 2);
    LEVEL(8, 3);  LEVEL(7, 4);  LEVEL(6, 5);

    // ---- XOR-swizzled transpose: reg bits <-> lane bits ----
    // write: lane t puts reg r at [t*64 + (r^t)]  (fixed r: banks = (r^t)%32,
    //   bijective in t -> exactly 2 lanes/bank = b32 minimum)
#pragma unroll
    for (int r = 0; r < 64; ++r) {
        const int a = (t << 6) | (r ^ t);
        Lr[a] = xr[r];
        Li[a] = xi[r];
    }
    __syncthreads();    // single wave: ~free; LDS is in-order per wave
    // read: new reg r' = old lane bits; amp (r'<<6)|t sits at [r'*64+(t^r')]
    //   (fixed r': addresses consecutive in t -> conflict-free)
#pragma unroll
    for (int r = 0; r < 64; ++r) {
        const int a = (r << 6) | (t ^ r);
        xr[r] = Lr[a];
        xi[r] = Li[a];
    }

    // ---- levels on state bits 6..11 (now register-local) -> gates 5..0 ----
    LEVEL(5, 0); LEVEL(4, 1); LEVEL(3, 2);
    LEVEL(2, 3); LEVEL(1, 4); LEVEL(0, 5);

    // ---- store: amp (r<<6)|t -> out[e*4096 + (r<<6)+t] as float2 ----
    // per instruction: 64 lanes x 8 B consecutive = 512 B, coalesced
    {
        float2* o2 = (float2*)out + (size_t)e * DIM;
#pragma unroll
        for (int r = 0; r < 64; ++r)
            o2[(r << 6) | t] = make_float2(xr[r], xi[r]);
    }
}

extern "C" void kernel_launch(void* const* d_in, const int* in_sizes, int n_in,
                              void* d_out, int out_size, void* d_ws, size_t ws_size,
                              hipStream_t stream) {
    const float* thetas = (const float*)d_in[0];
    const float* sre    = (const float*)d_in[1];
    const float* sim_   = (const float*)d_in[2];
    float* out = (float*)d_out;

    u3_wave_kernel<<<BATCH, 64, 0, stream>>>(thetas, sre, sim_, out);
}

// Round 9
// 17.285 us; speedup vs baseline: 1.3775x; 1.3775x over previous
//
#include <hip/hip_runtime.h>
#include <math.h>

#define NQ    12
#define DIM   4096
#define BATCH 512

// float2-granular padded LDS index: +2 float2 per 16.
// Bank audit (64-lane wave, 32 banks):
//  exch1 write (b128, idx=(k<<10)|(t<<2)):    uniform 8 words/bank  (optimal)
//  exch1 read  (b64,  idx=(u<<6)|(r<<2)|v):   8 words/bank on 16 banks (2x)
//  exch2 write (same slots as exch1 read):    2x
//  exch2 read  (b64,  idx=(r<<6)|w):          uniform 4 words/bank  (optimal)
#define PAD2(i) ((i) + 2 * ((i) >> 4))

// One butterfly level over the 16 register-resident float2 amplitudes.
// q = gate index (acts on state bit 11-q), J = local register bit.
#define LEVEL(q, J) do {                                                    \
    const float4 GA = *(const float4*)&g[q][0];                             \
    const float4 GB = *(const float4*)&g[q][4];                             \
    _Pragma("unroll")                                                       \
    for (int p = 0; p < 8; ++p) {                                           \
        const int r0 = ((p >> (J)) << ((J) + 1)) | (p & ((1 << (J)) - 1));  \
        const int r1 = r0 | (1 << (J));                                     \
        const float ar = x[r0].x, ai = x[r0].y;                             \
        const float br = x[r1].x, bi = x[r1].y;                             \
        x[r0].x = GA.x * ar - GA.y * ai + GA.z * br - GA.w * bi;            \
        x[r0].y = GA.x * ai + GA.y * ar + GA.z * bi + GA.w * br;            \
        x[r1].x = GB.x * ar - GB.y * ai + GB.z * br - GB.w * bi;            \
        x[r1].y = GB.x * ai + GB.y * ar + GB.z * bi + GB.w * br;            \
    }                                                                       \
} while (0)

__global__ __launch_bounds__(256) void u3_apply_kernel(
    const float* __restrict__ thetas,   // [12,3]
    const float* __restrict__ sre,      // [512,4096]
    const float* __restrict__ sim_,     // [512,4096]
    float*       __restrict__ out)      // [512,4096,2]
{
    __shared__ __align__(16) float2 L[4608];     // PAD2(4095)+1 = 4606
    __shared__ __align__(16) float  g[NQ][8];

    const int b = blockIdx.x;
    const int t = threadIdx.x;

    // ---- lane-CONTIGUOUS global loads: chunk k, float4 index k*256+t.
    //      Per instruction: 256 lanes x 16 B consecutive = 4 KB dense. ----
    const float4* pre = (const float4*)(sre  + (size_t)b * DIM);
    const float4* pim = (const float4*)(sim_ + (size_t)b * DIM);
    float4 vr0 = pre[t],       vr1 = pre[256 + t],
           vr2 = pre[512 + t], vr3 = pre[768 + t];
    float4 vi0 = pim[t],       vi1 = pim[256 + t],
           vi2 = pim[512 + t], vi3 = pim[768 + t];

    // ---- gates (threads 0..11); gate q acts on state bit (11-q) ----
    if (t < NQ) {
        float th = thetas[t * 3 + 0];
        float ph = thetas[t * 3 + 1];
        float la = thetas[t * 3 + 2];
        float c, s, cl, sl, cp, sp;
        __sincosf(th * 0.5f, &s, &c);
        __sincosf(la, &sl, &cl);
        __sincosf(ph, &sp, &cp);
        g[t][0] = c;        g[t][1] = 0.0f;
        g[t][2] = -cl * s;  g[t][3] = -sl * s;
        g[t][4] = cp * s;   g[t][5] = sp * s;
        g[t][6] = (cp * cl - sp * sl) * c;
        g[t][7] = (sp * cl + cp * sl) * c;
    }
    __syncthreads();    // #1: gates visible

    // ---- unpack: reg r=(k<<2)|j holds amp idx=(k<<10)|(t<<2)|j,
    //      i.e. thread-local idx bits are {11,10,1,0} ----
    float2 x[16];
    x[ 0] = make_float2(vr0.x, vi0.x); x[ 1] = make_float2(vr0.y, vi0.y);
    x[ 2] = make_float2(vr0.z, vi0.z); x[ 3] = make_float2(vr0.w, vi0.w);
    x[ 4] = make_float2(vr1.x, vi1.x); x[ 5] = make_float2(vr1.y, vi1.y);
    x[ 6] = make_float2(vr1.z, vi1.z); x[ 7] = make_float2(vr1.w, vi1.w);
    x[ 8] = make_float2(vr2.x, vi2.x); x[ 9] = make_float2(vr2.y, vi2.y);
    x[10] = make_float2(vr2.z, vi2.z); x[11] = make_float2(vr2.w, vi2.w);
    x[12] = make_float2(vr3.x, vi3.x); x[13] = make_float2(vr3.y, vi3.y);
    x[14] = make_float2(vr3.z, vi3.z); x[15] = make_float2(vr3.w, vi3.w);

    // ---- stage A: idx bits 0,1 (reg 0,1) and 10,11 (reg 2,3)
    //      -> gates 11,10 and 1,0 ----
    LEVEL(11, 0); LEVEL(10, 1); LEVEL(1, 2); LEVEL(0, 3);

    // ---- exchange 1: write b128 pairs at idx=(k<<10)|(t<<2);
    //      read -> reg = idx bits 5:2, thread owns bits {11:6, 1:0} ----
#pragma unroll
    for (int k = 0; k < 4; ++k) {
        const int pa = PAD2((k << 10) | (t << 2));
        *(float4*)&L[pa] =
            make_float4(x[4 * k].x,     x[4 * k].y,
                        x[4 * k + 1].x, x[4 * k + 1].y);
        *(float4*)&L[pa + 2] =
            make_float4(x[4 * k + 2].x, x[4 * k + 2].y,
                        x[4 * k + 3].x, x[4 * k + 3].y);
    }
    __syncthreads();    // #2
    const int base1 = ((t >> 2) << 6) | (t & 3);     // bits 11:6 | 1:0
#pragma unroll
    for (int r = 0; r < 16; ++r) x[r] = L[PAD2(base1 | (r << 2))];

    // ---- stage B: idx bits 2,3,4,5 -> gates 9,8,7,6 ----
    LEVEL(9, 0); LEVEL(8, 1); LEVEL(7, 2); LEVEL(6, 3);

    // ---- exchange 2: write back SAME slots (no cross-thread WAR),
    //      read -> reg = idx bits 9:6, thread owns bits {11,10, 5:0} ----
#pragma unroll
    for (int r = 0; r < 16; ++r) L[PAD2(base1 | (r << 2))] = x[r];
    __syncthreads();    // #3
    const int base2 = ((t >> 6) << 10) | (t & 63);   // bits 11:10 | 5:0
#pragma unroll
    for (int r = 0; r < 16; ++r) x[r] = L[PAD2(base2 | (r << 6))];

    // ---- stage C: idx bits 6,7,8,9 -> gates 5,4,3,2 ----
    LEVEL(5, 0); LEVEL(4, 1); LEVEL(3, 2); LEVEL(2, 3);

    // ---- store: idx = base2|(r<<6); fixed r: lanes 0..63 contiguous
    //      float2 = 512 B per wave instruction ----
    {
        float2* o2 = (float2*)out + (size_t)b * DIM;
#pragma unroll
        for (int r = 0; r < 16; ++r) o2[base2 | (r << 6)] = x[r];
    }
}

extern "C" void kernel_launch(void* const* d_in, const int* in_sizes, int n_in,
                              void* d_out, int out_size, void* d_ws, size_t ws_size,
                              hipStream_t stream) {
    const float* thetas = (const float*)d_in[0];
    const float* sre    = (const float*)d_in[1];
    const float* sim_   = (const float*)d_in[2];
    float* out = (float*)d_out;

    u3_apply_kernel<<<BATCH, 256, 0, stream>>>(thetas, sre, sim_, out);
}